// Round 2
// baseline (23525.749 us; speedup 1.0000x reference)
//
#include <hip/hip_runtime.h>
#include <stdint.h>

// RNNTextClassifier: B=64, S=512, E=H=512, NCLS=8
// Round 5: XCD-local fast-path sync, HANG-PROOF version of Round 4.
// Round 4 timed out: unbounded spin on sc0-store -> sc0-load visibility,
// which is unproven on gfx950 (suspect: sc0 load serviced past local L2
// while sc0 store leaves line dirty in L2 -> stale poll forever).
// Fix: every fast poll is BOUNDED (SPIN_LIMIT); on exhaustion the wave
// sticks to the slow (Round-3-proven, sc0 sc1 device-scope) path.
// Producers always dual-publish (sc0 fast buf + sc0 sc1 slow buf), so any
// mixture of consumer-side fast/slow decisions is correct by construction.
// ws: hsl_f 1MB @0, hsl_s 1MB @1MB, xcc_tbl 512B @2MB (memset each launch).

#define BB 64
#define SS 512
#define HH 512
#define HSLN (2 * 4 * 64 * 512)  // u32 per hsl buffer (1 MB)
#define SPIN_LIMIT 4096
#define HS_LIMIT 65536

typedef short bf16x8 __attribute__((ext_vector_type(8)));
typedef float f32x4 __attribute__((ext_vector_type(4)));
typedef int i32x4 __attribute__((ext_vector_type(4)));
typedef unsigned int u32;
typedef u32 u32x2 __attribute__((ext_vector_type(2)));

__device__ __forceinline__ unsigned short f2bf(float f) {
  uint32_t u = __builtin_bit_cast(uint32_t, f);
  u += 0x7FFFu + ((u >> 16) & 1u);
  return (unsigned short)(u >> 16);
}
__device__ __forceinline__ float bf2f(unsigned short h) {
  uint32_t u = ((uint32_t)h) << 16;
  return __builtin_bit_cast(float, u);
}
__device__ __forceinline__ int pack2(unsigned short a, unsigned short b) {
  return (int)(unsigned int)a | ((int)(unsigned int)b << 16);
}
__device__ __forceinline__ u32 hipack(u32 a, u32 b) {
  return (a >> 16) | (b & 0xFFFF0000u);
}
__device__ __forceinline__ u32 lopack(u32 a, u32 b) {
  return (a & 0xFFF8u) | ((b & 0xFFF8u) << 16);
}
__device__ __forceinline__ bool tag4(i32x4 v, u32 t) {
  u32 m = (((u32)v[0] ^ t) | ((u32)v[1] ^ t) | ((u32)v[2] ^ t) | ((u32)v[3] ^ t)) & 7u;
  return m == 0u;
}

// device-coherent (slow) ops: bypass all non-common caches
#define UC_LOAD4(dst, ptr) \
  asm volatile("global_load_dwordx4 %0, %1, off sc0 sc1" : "=v"(dst) : "v"(ptr))
#define UC_LOAD1(dst, ptr) \
  asm volatile("global_load_dword %0, %1, off sc0 sc1" : "=v"(dst) : "v"(ptr))
#define UC_STORE2(ptr, v) \
  asm volatile("global_store_dwordx2 %0, %1, off sc0 sc1" ::"v"(ptr), "v"(v) : "memory")
#define UC_STORE1(ptr, v) \
  asm volatile("global_store_dword %0, %1, off sc0 sc1" ::"v"(ptr), "v"(v) : "memory")
// XCD-local (fast) ops: bypass L1 only; intended coherence point = shared L2
#define F_LOAD4(dst, ptr) \
  asm volatile("global_load_dwordx4 %0, %1, off sc0" : "=v"(dst) : "v"(ptr))
#define F_LOAD1(dst, ptr) \
  asm volatile("global_load_dword %0, %1, off sc0" : "=v"(dst) : "v"(ptr))
#define F_STORE2(ptr, v) \
  asm volatile("global_store_dwordx2 %0, %1, off sc0" ::"v"(ptr), "v"(v) : "memory")

__global__ __launch_bounds__(512, 2) void k_rnn(
    const int* __restrict__ x, const float* __restrict__ emb,
    const float* __restrict__ Wih0, const float* __restrict__ Whh0,
    const float* __restrict__ bih0, const float* __restrict__ bhh0,
    const float* __restrict__ Wih1, const float* __restrict__ Whh1,
    const float* __restrict__ bih1, const float* __restrict__ bhh1,
    u32* __restrict__ ws) {
  const int bid = blockIdx.x;
  if ((bid & 7) >= 4) return;  // dummies keep round-robin phase
  const int tid = threadIdx.x;
  const int bg = bid & 7;       // 0..3 == target XCD
  const int kk = bid >> 3;      // 0..15 within group
  const int layer = kk >> 3;    // 0 or 1
  const int c = kk & 7;         // hidden slice (64 dims)
  const int wid = tid >> 6;
  const int lane = tid & 63;
  const int kq = wid >> 1;  // K-quarter
  const int nh = wid & 1;   // N-half (32 cols)

  u32* __restrict__ hslf = ws;             // fast buffer (XCD L2 scope)
  u32* __restrict__ hsls = ws + HSLN;      // slow buffer (device scope)
  u32* __restrict__ xcct = ws + 2 * HSLN;  // xcc handshake table

  __shared__ __align__(16) unsigned short s_in0[16 * 512];
  __shared__ __align__(16) unsigned short s_Hhi[16 * 512];
  __shared__ __align__(16) unsigned short s_Hlo[16 * 512];
  __shared__ __align__(16) float s_part[4 * 16 * 64];

  const float* Wih = layer ? Wih1 : Wih0;
  const float* Whh = layer ? Whh1 : Whh0;
  const float* bi = layer ? bih1 : bih0;
  const float* bh = layer ? bhh1 : bhh0;

  // ---- publish own XCC id (device scope) ----
  u32 xcc;
  asm volatile("s_getreg_b32 %0, hwreg(HW_REG_XCC_ID)" : "=s"(xcc));
  xcc &= 0xFFu;
  if (tid == 0) {
    u32 v = 0x100u | xcc;
    u32* p = xcct + bid;
    UC_STORE1(p, v);
  }

  // ---- one-time: W fragments into VGPRs (overlaps handshake latency) ----
  bf16x8 wih[2][4], whhh[2][4], whhl[2][4];
  {
    const int r16 = lane & 15, kg = lane >> 4;
#pragma unroll
    for (int nt = 0; nt < 2; ++nt) {
#pragma unroll
      for (int kt = 0; kt < 4; ++kt) {
        int row = c * 64 + nh * 32 + nt * 16 + r16;
        int k0 = kq * 128 + kt * 32 + kg * 8;
        const float* p = Wih + row * 512 + k0;
        bf16x8 v;
#pragma unroll
        for (int j = 0; j < 8; ++j) v[j] = (short)f2bf(p[j]);
        wih[nt][kt] = v;
        const float* q = Whh + row * 512 + k0;
        bf16x8 vh, vl;
#pragma unroll
        for (int j = 0; j < 8; ++j) {
          float f = q[j];
          unsigned short h = f2bf(f);
          vh[j] = (short)h;
          vl[j] = (short)f2bf(f - bf2f(h));
        }
        whhh[nt][kt] = vh;
        whhl[nt][kt] = vl;
      }
    }
  }
  float biasv0, biasv1;
  {
    int na = (tid & 31) * 2;
    biasv0 = bi[c * 64 + na] + bh[c * 64 + na];
    biasv1 = bi[c * 64 + na + 1] + bh[c * 64 + na + 1];
  }

  const int r_st = tid >> 5;  // staging row 0..15
  const int ch = tid & 31;    // 16-element chunk of 512

  // prefetch in0 for step 1 (layer0: emb gather t=0)
  float4 pf0, pf1, pf2, pf3;
  if (layer == 0) {
    int rid = x[(bg * 16 + r_st) * SS + 0];
    const float4* ep = (const float4*)(emb + (size_t)rid * 512 + ch * 16);
    pf0 = ep[0]; pf1 = ep[1]; pf2 = ep[2]; pf3 = ep[3];
  }

  // ---- handshake (BOUNDED): are all 16 group members on my XCC? ----
  bool fast_ok;
  {
    const u32* pt = xcct + bg + 8 * (lane & 15);
    u32 e = 0;
    int spins = 0;
    bool done = false;
    while (true) {
      UC_LOAD1(e, pt);
      asm volatile("s_waitcnt vmcnt(0)" : "+v"(e)::"memory");
      if (__all((e & 0x100u) != 0u)) { done = true; break; }
      if (++spins > HS_LIMIT) break;
    }
    fast_ok = done && __all((e & 0xFFu) == xcc);
  }

  for (int s = 1; s <= SS; ++s) {
    // ================= phase 1: poll on tagged data =================
    i32x4 h0 = {0, 0, 0, 0}, h1 = {0, 0, 0, 0}, h2 = {0, 0, 0, 0}, h3 = {0, 0, 0, 0};
    const u32 exp_h = (u32)((s - 1) & 7);
    const size_t off_h =
        (((size_t)layer * 4 + ((s - 1) & 3)) * 64 + bg * 16 + r_st) * 512 + ch * 16;
    if (layer == 0) {
      if (s > 1) {
        bool got = false;
        if (fast_ok) {
          // fast h-poll: bounded L2 spin
          const u32* ph = hslf + off_h;
          int spins = 0;
          while (true) {
            F_LOAD4(h0, ph);
            F_LOAD4(h1, ph + 4);
            F_LOAD4(h2, ph + 8);
            F_LOAD4(h3, ph + 12);
            asm volatile("s_waitcnt vmcnt(0)"
                         : "+v"(h0), "+v"(h1), "+v"(h2), "+v"(h3)::"memory");
            bool ok = tag4(h0, exp_h) && tag4(h1, exp_h) && tag4(h2, exp_h) &&
                      tag4(h3, exp_h);
            if (__all(ok)) { got = true; break; }
            if (++spins > SPIN_LIMIT) break;
          }
          if (!got) fast_ok = false;  // sticky fallback
        }
        if (!got) {
          const u32* ph = hsls + off_h;
          while (true) {
            UC_LOAD4(h0, ph);
            UC_LOAD4(h1, ph + 4);
            UC_LOAD4(h2, ph + 8);
            UC_LOAD4(h3, ph + 12);
            asm volatile("s_waitcnt vmcnt(0)"
                         : "+v"(h0), "+v"(h1), "+v"(h2), "+v"(h3)::"memory");
            bool ok = tag4(h0, exp_h) && tag4(h1, exp_h) && tag4(h2, exp_h) &&
                      tag4(h3, exp_h);
            if (__all(ok)) break;
          }
        }
        // back-pressure poll (wave 0 only; B2 syncthreads covers the block)
        if (s > 4 && wid == 0) {
          const u32 exp_bp = (u32)((s - 4) & 7);
          const size_t off_bp =
              ((size_t)(4 + ((s - 4) & 3)) * 64 + bg * 16) * 512 +
              (lane < 8 ? lane * 64 : 0);
          bool bgot = false;
          if (fast_ok) {
            const u32* pbp = hslf + off_bp;
            int spins = 0;
            while (true) {
              u32 bpw = 0;
              F_LOAD1(bpw, pbp);
              asm volatile("s_waitcnt vmcnt(0)" : "+v"(bpw)::"memory");
              if (__all(lane >= 8 || ((bpw & 7u) == exp_bp))) { bgot = true; break; }
              if (++spins > SPIN_LIMIT) break;
            }
            if (!bgot) fast_ok = false;
          }
          if (!bgot) {
            const u32* pbp = hsls + off_bp;
            while (true) {
              u32 bpw = 0;
              UC_LOAD1(bpw, pbp);
              asm volatile("s_waitcnt vmcnt(0)" : "+v"(bpw)::"memory");
              if (__all(lane >= 8 || ((bpw & 7u) == exp_bp))) break;
            }
          }
        }
      }
    } else {
      // layer1: poll in0 = out0[s] (always) + own-layer H (s>1)
      i32x4 i0 = {0, 0, 0, 0}, i1 = {0, 0, 0, 0}, i2 = {0, 0, 0, 0}, i3 = {0, 0, 0, 0};
      const u32 exp_i = (u32)(s & 7);
      const size_t off_i =
          (((size_t)(s & 3)) * 64 + bg * 16 + r_st) * 512 + ch * 16;
      const bool need_h = (s > 1);
      bool got = false;
      if (fast_ok) {
        const u32* pi = hslf + off_i;
        const u32* ph = hslf + off_h;
        int spins = 0;
        while (true) {
          F_LOAD4(i0, pi);
          F_LOAD4(i1, pi + 4);
          F_LOAD4(i2, pi + 8);
          F_LOAD4(i3, pi + 12);
          F_LOAD4(h0, ph);
          F_LOAD4(h1, ph + 4);
          F_LOAD4(h2, ph + 8);
          F_LOAD4(h3, ph + 12);
          asm volatile("s_waitcnt vmcnt(0)"
                       : "+v"(i0), "+v"(i1), "+v"(i2), "+v"(i3), "+v"(h0), "+v"(h1),
                         "+v"(h2), "+v"(h3)::"memory");
          bool ok = tag4(i0, exp_i) && tag4(i1, exp_i) && tag4(i2, exp_i) &&
                    tag4(i3, exp_i) &&
                    (!need_h || (tag4(h0, exp_h) && tag4(h1, exp_h) &&
                                 tag4(h2, exp_h) && tag4(h3, exp_h)));
          if (__all(ok)) { got = true; break; }
          if (++spins > SPIN_LIMIT) break;
        }
        if (!got) fast_ok = false;
      }
      if (!got) {
        const u32* pi = hsls + off_i;
        const u32* ph = hsls + off_h;
        while (true) {
          UC_LOAD4(i0, pi);
          UC_LOAD4(i1, pi + 4);
          UC_LOAD4(i2, pi + 8);
          UC_LOAD4(i3, pi + 12);
          UC_LOAD4(h0, ph);
          UC_LOAD4(h1, ph + 4);
          UC_LOAD4(h2, ph + 8);
          UC_LOAD4(h3, ph + 12);
          asm volatile("s_waitcnt vmcnt(0)"
                       : "+v"(i0), "+v"(i1), "+v"(i2), "+v"(i3), "+v"(h0), "+v"(h1),
                         "+v"(h2), "+v"(h3)::"memory");
          bool ok = tag4(i0, exp_i) && tag4(i1, exp_i) && tag4(i2, exp_i) &&
                    tag4(i3, exp_i) &&
                    (!need_h || (tag4(h0, exp_h) && tag4(h1, exp_h) &&
                                 tag4(h2, exp_h) && tag4(h3, exp_h)));
          if (__all(ok)) break;
        }
      }
      // stage in0 (hi halves only) into swizzled LDS
      i32x4 A0 = {(int)hipack(i0[0], i0[1]), (int)hipack(i0[2], i0[3]),
                  (int)hipack(i1[0], i1[1]), (int)hipack(i1[2], i1[3])};
      i32x4 A1 = {(int)hipack(i2[0], i2[1]), (int)hipack(i2[2], i2[3]),
                  (int)hipack(i3[0], i3[1]), (int)hipack(i3[2], i3[3])};
      *(i32x4*)(s_in0 + r_st * 512 + (((2 * ch) ^ (r_st & 7)) << 3)) = A0;
      *(i32x4*)(s_in0 + r_st * 512 + (((2 * ch + 1) ^ (r_st & 7)) << 3)) = A1;
    }

    // ---- stage in0 for layer0 (from prefetched emb f32) ----
    if (layer == 0) {
      i32x4 v0, v1;
      v0[0] = pack2(f2bf(pf0.x), f2bf(pf0.y));
      v0[1] = pack2(f2bf(pf0.z), f2bf(pf0.w));
      v0[2] = pack2(f2bf(pf1.x), f2bf(pf1.y));
      v0[3] = pack2(f2bf(pf1.z), f2bf(pf1.w));
      v1[0] = pack2(f2bf(pf2.x), f2bf(pf2.y));
      v1[1] = pack2(f2bf(pf2.z), f2bf(pf2.w));
      v1[2] = pack2(f2bf(pf3.x), f2bf(pf3.y));
      v1[3] = pack2(f2bf(pf3.z), f2bf(pf3.w));
      *(i32x4*)(s_in0 + r_st * 512 + (((2 * ch) ^ (r_st & 7)) << 3)) = v0;
      *(i32x4*)(s_in0 + r_st * 512 + (((2 * ch + 1) ^ (r_st & 7)) << 3)) = v1;
    }
    // ---- stage H hi/lo (deinterleave tagged words) ----
    if (s > 1) {
      i32x4 A0 = {(int)hipack(h0[0], h0[1]), (int)hipack(h0[2], h0[3]),
                  (int)hipack(h1[0], h1[1]), (int)hipack(h1[2], h1[3])};
      i32x4 A1 = {(int)hipack(h2[0], h2[1]), (int)hipack(h2[2], h2[3]),
                  (int)hipack(h3[0], h3[1]), (int)hipack(h3[2], h3[3])};
      i32x4 B0 = {(int)lopack(h0[0], h0[1]), (int)lopack(h0[2], h0[3]),
                  (int)lopack(h1[0], h1[1]), (int)lopack(h1[2], h1[3])};
      i32x4 B1 = {(int)lopack(h2[0], h2[1]), (int)lopack(h2[2], h2[3]),
                  (int)lopack(h3[0], h3[1]), (int)lopack(h3[2], h3[3])};
      *(i32x4*)(s_Hhi + r_st * 512 + (((2 * ch) ^ (r_st & 7)) << 3)) = A0;
      *(i32x4*)(s_Hhi + r_st * 512 + (((2 * ch + 1) ^ (r_st & 7)) << 3)) = A1;
      *(i32x4*)(s_Hlo + r_st * 512 + (((2 * ch) ^ (r_st & 7)) << 3)) = B0;
      *(i32x4*)(s_Hlo + r_st * 512 + (((2 * ch + 1) ^ (r_st & 7)) << 3)) = B1;
    }
    __syncthreads();  // B2

    // ---- prefetch next emb row (layer0, off critical path) ----
    if (layer == 0 && s < SS) {
      int rid = x[(bg * 16 + r_st) * SS + s];
      const float4* ep = (const float4*)(emb + (size_t)rid * 512 + ch * 16);
      pf0 = ep[0]; pf1 = ep[1]; pf2 = ep[2]; pf3 = ep[3];
    }

    // ---- MFMA ----
    f32x4 acc0 = {0.f, 0.f, 0.f, 0.f};
    f32x4 acc1 = {0.f, 0.f, 0.f, 0.f};
    {
      const int r16 = lane & 15, kg = lane >> 4;
#pragma unroll
      for (int kt = 0; kt < 4; ++kt) {
        int k8 = kq * 16 + kt * 4 + kg;
        bf16x8 ain = __builtin_bit_cast(
            bf16x8, *(const i32x4*)(s_in0 + r16 * 512 + ((k8 ^ (r16 & 7)) << 3)));
        acc0 = __builtin_amdgcn_mfma_f32_16x16x32_bf16(ain, wih[0][kt], acc0, 0, 0, 0);
        acc1 = __builtin_amdgcn_mfma_f32_16x16x32_bf16(ain, wih[1][kt], acc1, 0, 0, 0);
      }
      if (s > 1) {
#pragma unroll
        for (int kt = 0; kt < 4; ++kt) {
          int k8 = kq * 16 + kt * 4 + kg;
          bf16x8 ahi = __builtin_bit_cast(
              bf16x8, *(const i32x4*)(s_Hhi + r16 * 512 + ((k8 ^ (r16 & 7)) << 3)));
          bf16x8 alo = __builtin_bit_cast(
              bf16x8, *(const i32x4*)(s_Hlo + r16 * 512 + ((k8 ^ (r16 & 7)) << 3)));
          acc0 = __builtin_amdgcn_mfma_f32_16x16x32_bf16(ahi, whhh[0][kt], acc0, 0, 0, 0);
          acc0 = __builtin_amdgcn_mfma_f32_16x16x32_bf16(ahi, whhl[0][kt], acc0, 0, 0, 0);
          acc0 = __builtin_amdgcn_mfma_f32_16x16x32_bf16(alo, whhh[0][kt], acc0, 0, 0, 0);
          acc1 = __builtin_amdgcn_mfma_f32_16x16x32_bf16(ahi, whhh[1][kt], acc1, 0, 0, 0);
          acc1 = __builtin_amdgcn_mfma_f32_16x16x32_bf16(ahi, whhl[1][kt], acc1, 0, 0, 0);
          acc1 = __builtin_amdgcn_mfma_f32_16x16x32_bf16(alo, whhh[1][kt], acc1, 0, 0, 0);
        }
      }
#pragma unroll
      for (int j = 0; j < 4; ++j) {
        int m = kg * 4 + j;
        int xr = (m >> 2) & 3;
        int n0i = nh * 32 + 0 * 16 + r16;
        int n1i = nh * 32 + 1 * 16 + r16;
        s_part[kq * 1024 + m * 64 + (n0i ^ (xr << 4))] = acc0[j];
        s_part[kq * 1024 + m * 64 + (n1i ^ (xr << 4))] = acc1[j];
      }
    }
    __syncthreads();  // B3

    // ---- finals: reduce, bias, tanh, pack word (hi|lo|tag), dual-publish ----
    {
      int m = tid >> 5, na = (tid & 31) * 2;
      int xr = (m >> 2) & 3;
      float v0 = biasv0, v1 = biasv1;
#pragma unroll
      for (int q2 = 0; q2 < 4; ++q2) {
        const float2* sp =
            (const float2*)(s_part + q2 * 1024 + m * 64 + (na ^ (xr << 4)));
        float2 t = *sp;
        v0 += t.x;
        v1 += t.y;
      }
      v0 = tanhf(v0);
      v1 = tanhf(v1);
      unsigned short a0 = f2bf(v0), a1 = f2bf(v1);
      unsigned short b0 = f2bf(v0 - bf2f(a0)), b1 = f2bf(v1 - bf2f(a1));
      u32 tag = (u32)(s & 7);
      u32x2 wv;
      wv[0] = ((u32)a0 << 16) | ((u32)b0 & 0xFFF8u) | tag;
      wv[1] = ((u32)a1 << 16) | ((u32)b1 & 0xFFF8u) | tag;
      size_t off = (((size_t)layer * 4 + (s & 3)) * 64 + bg * 16 + m) * 512 +
                   c * 64 + na;
      F_STORE2(hslf + off, wv);   // fast: XCD-L2 visible (best effort)
      UC_STORE2(hsls + off, wv);  // slow: device visible (fallback + k_fc)
    }
    // no drain, no flag: consumers detect via embedded tags
  }
}

__global__ void k_fc(const u32* __restrict__ h1w, const float* __restrict__ fcW,
                     const float* __restrict__ fcb, float* __restrict__ out) {
  int i = threadIdx.x;  // 512 = 64 batch x 8 classes
  int b = i >> 3, cc = i & 7;
  float acc = fcb[cc];
  const u32* ph = h1w + b * 512;
  const float* pw = fcW + cc * 512;
  for (int k = 0; k < 512; k += 4) {
    int4 w4 = *(const int4*)(ph + k);
    float4 wv = *(const float4*)(pw + k);
    acc += (bf2f((unsigned short)((u32)w4.x >> 16)) +
            bf2f((unsigned short)((u32)w4.x & 0xFFF8u))) * wv.x;
    acc += (bf2f((unsigned short)((u32)w4.y >> 16)) +
            bf2f((unsigned short)((u32)w4.y & 0xFFF8u))) * wv.y;
    acc += (bf2f((unsigned short)((u32)w4.z >> 16)) +
            bf2f((unsigned short)((u32)w4.z & 0xFFF8u))) * wv.z;
    acc += (bf2f((unsigned short)((u32)w4.w >> 16)) +
            bf2f((unsigned short)((u32)w4.w & 0xFFF8u))) * wv.w;
  }
  out[b * 8 + cc] = acc;
}

extern "C" void kernel_launch(void* const* d_in, const int* in_sizes, int n_in,
                              void* d_out, int out_size, void* d_ws, size_t ws_size,
                              hipStream_t stream) {
  const int* x = (const int*)d_in[0];
  const float* emb = (const float*)d_in[1];
  const float* Wih0 = (const float*)d_in[2];
  const float* Whh0 = (const float*)d_in[3];
  const float* bih0 = (const float*)d_in[4];
  const float* bhh0 = (const float*)d_in[5];
  const float* Wih1 = (const float*)d_in[6];
  const float* Whh1 = (const float*)d_in[7];
  const float* bih1 = (const float*)d_in[8];
  const float* bhh1 = (const float*)d_in[9];
  const float* fcW = (const float*)d_in[10];
  const float* fcb = (const float*)d_in[11];

  u32* ws = (u32*)d_ws;  // hsl_f 1MB | hsl_s 1MB | xcc_tbl 512B

  hipMemsetAsync(ws, 0, ((size_t)2 * HSLN + 128) * sizeof(u32), stream);
  // grid=128: blocks with bid%8>=4 exit immediately; active 64 blocks are
  // steered so each batch-group's 16-block clique shares one XCD (bid%8).
  hipLaunchKernelGGL(k_rnn, dim3(128), dim3(512), 0, stream, x, emb, Wih0, Whh0,
                     bih0, bhh0, Wih1, Whh1, bih1, bhh1, ws);
  // final h1 = step 512 -> layer1 slot (512&3)==0, from the device-scope buffer
  hipLaunchKernelGGL(k_fc, dim3(1), dim3(512), 0, stream,
                     ws + HSLN + (size_t)4 * 64 * 512, fcW, fcb, (float*)d_out);
}

// Round 3
// 2216.337 us; speedup vs baseline: 10.6147x; 10.6147x over previous
//
#include <hip/hip_runtime.h>
#include <stdint.h>

// RNNTextClassifier: B=64, S=512, E=H=512, NCLS=8
// Round 6: revert to Round-3 tagged-data device-scope protocol (proven
// 2360us). Rounds 4/5 refuted the XCD-local sc0 fast path (livelock /
// 10x slowdown from dual-publish L2 line stealing). This round keeps the
// proven sync byte-for-byte and shaves two measured local costs:
//  1) s_part stride 64 -> 68 f32: kills the 4-way LDS bank conflict on
//     partial-sum writes (SQ_LDS_BANK_CONFLICT 2.5e7 -> ~1.2e7 predicted).
//  2) tanhf -> overflow-safe exp2-based tanh (v_exp_f32, ~25cy vs ~80cy).
// Ring: hsl[layer][slot=s&3][row 0..63][col 0..511] u32; tag = s&7.
// Layer0 back-pressure polls layer1 progress before slot overwrite.
// ws: hsl 1MB at offset 0 (memset to 0 each launch).

#define BB 64
#define SS 512
#define HH 512

typedef short bf16x8 __attribute__((ext_vector_type(8)));
typedef float f32x4 __attribute__((ext_vector_type(4)));
typedef int i32x4 __attribute__((ext_vector_type(4)));
typedef unsigned int u32;
typedef u32 u32x2 __attribute__((ext_vector_type(2)));

#define SPART_LD 68          // padded stride (f32) per m-row: m*68 % 32 spreads banks
#define SPART_Q (16 * SPART_LD)  // per-K-quarter block

__device__ __forceinline__ unsigned short f2bf(float f) {
  uint32_t u = __builtin_bit_cast(uint32_t, f);
  u += 0x7FFFu + ((u >> 16) & 1u);
  return (unsigned short)(u >> 16);
}
__device__ __forceinline__ float bf2f(unsigned short h) {
  uint32_t u = ((uint32_t)h) << 16;
  return __builtin_bit_cast(float, u);
}
__device__ __forceinline__ int pack2(unsigned short a, unsigned short b) {
  return (int)(unsigned int)a | ((int)(unsigned int)b << 16);
}
// pack hi halves of two words into one u32 (elem a -> low half, b -> high)
__device__ __forceinline__ u32 hipack(u32 a, u32 b) {
  return (a >> 16) | (b & 0xFFFF0000u);
}
// pack lo halves (tag bits stripped)
__device__ __forceinline__ u32 lopack(u32 a, u32 b) {
  return (a & 0xFFF8u) | ((b & 0xFFF8u) << 16);
}
__device__ __forceinline__ bool tag4(i32x4 v, u32 t) {
  u32 m = (((u32)v[0] ^ t) | ((u32)v[1] ^ t) | ((u32)v[2] ^ t) | ((u32)v[3] ^ t)) & 7u;
  return m == 0u;
}
// fast tanh: t = sign(v) * (1 - e)/(1 + e), e = exp(-2|v|). No overflow,
// monotone, |err| ~1e-7. Uses HW v_exp_f32 via __expf.
__device__ __forceinline__ float fast_tanh(float v) {
  float a = __builtin_fabsf(v);
  float e = __expf(-2.0f * a);
  float t = (1.0f - e) / (1.0f + e);
  return __builtin_copysignf(t, v);
}

// device-coherent (UC) loads/stores: bypass non-common caches
#define UC_LOAD4(dst, ptr) \
  asm volatile("global_load_dwordx4 %0, %1, off sc0 sc1" : "=v"(dst) : "v"(ptr))
#define UC_LOAD1(dst, ptr) \
  asm volatile("global_load_dword %0, %1, off sc0 sc1" : "=v"(dst) : "v"(ptr))
#define UC_STORE2(ptr, v) \
  asm volatile("global_store_dwordx2 %0, %1, off sc0 sc1" ::"v"(ptr), "v"(v) : "memory")

__global__ __launch_bounds__(512, 2) void k_rnn(
    const int* __restrict__ x, const float* __restrict__ emb,
    const float* __restrict__ Wih0, const float* __restrict__ Whh0,
    const float* __restrict__ bih0, const float* __restrict__ bhh0,
    const float* __restrict__ Wih1, const float* __restrict__ Whh1,
    const float* __restrict__ bih1, const float* __restrict__ bhh1,
    u32* __restrict__ hsl) {
  const int tid = threadIdx.x;
  const int bid = blockIdx.x;
  const int layer = bid >> 5;  // 0 or 1
  const int lb = bid & 31;
  const int bg = lb >> 3;  // batch group (16 rows)
  const int c = lb & 7;    // hidden slice (64 dims)
  const int wid = tid >> 6;
  const int lane = tid & 63;
  const int kq = wid >> 1;  // K-quarter
  const int nh = wid & 1;   // N-half (32 cols)

  __shared__ __align__(16) unsigned short s_in0[16 * 512];
  __shared__ __align__(16) unsigned short s_Hhi[16 * 512];
  __shared__ __align__(16) unsigned short s_Hlo[16 * 512];
  __shared__ __align__(16) float s_part[4 * SPART_Q];

  const float* Wih = layer ? Wih1 : Wih0;
  const float* Whh = layer ? Whh1 : Whh0;
  const float* bi = layer ? bih1 : bih0;
  const float* bh = layer ? bhh1 : bhh0;

  // ---- one-time: W fragments into VGPRs ----
  bf16x8 wih[2][4], whhh[2][4], whhl[2][4];
  {
    const int r16 = lane & 15, kg = lane >> 4;
#pragma unroll
    for (int nt = 0; nt < 2; ++nt) {
#pragma unroll
      for (int kt = 0; kt < 4; ++kt) {
        int row = c * 64 + nh * 32 + nt * 16 + r16;
        int k0 = kq * 128 + kt * 32 + kg * 8;
        const float* p = Wih + row * 512 + k0;
        bf16x8 v;
#pragma unroll
        for (int j = 0; j < 8; ++j) v[j] = (short)f2bf(p[j]);
        wih[nt][kt] = v;
        const float* q = Whh + row * 512 + k0;
        bf16x8 vh, vl;
#pragma unroll
        for (int j = 0; j < 8; ++j) {
          float f = q[j];
          unsigned short h = f2bf(f);
          vh[j] = (short)h;
          vl[j] = (short)f2bf(f - bf2f(h));
        }
        whhh[nt][kt] = vh;
        whhl[nt][kt] = vl;
      }
    }
  }
  float biasv0, biasv1;
  {
    int na = (tid & 31) * 2;
    biasv0 = bi[c * 64 + na] + bh[c * 64 + na];
    biasv1 = bi[c * 64 + na + 1] + bh[c * 64 + na + 1];
  }

  const int r_st = tid >> 5;  // staging row 0..15
  const int ch = tid & 31;    // 16-element chunk of 512

  // prefetch in0 for step 1 (layer0: emb gather t=0)
  float4 pf0, pf1, pf2, pf3;
  if (layer == 0) {
    int rid = x[(bg * 16 + r_st) * SS + 0];
    const float4* ep = (const float4*)(emb + (size_t)rid * 512 + ch * 16);
    pf0 = ep[0]; pf1 = ep[1]; pf2 = ep[2]; pf3 = ep[3];
  }

  for (int s = 1; s <= SS; ++s) {
    // ================= phase 1: poll on tagged data =================
    i32x4 h0 = {0, 0, 0, 0}, h1 = {0, 0, 0, 0}, h2 = {0, 0, 0, 0}, h3 = {0, 0, 0, 0};
    const u32 exp_h = (u32)((s - 1) & 7);
    const u32* ph = hsl +
        (((size_t)layer * 4 + ((s - 1) & 3)) * 64 + bg * 16 + r_st) * 512 + ch * 16;
    if (layer == 0) {
      if (s > 1) {
        const bool need_bp = (s > 4) && (tid < 8);
        const u32 exp_bp = (u32)((s - 4) & 7);
        const u32* pbp = hsl + ((size_t)(4 + ((s - 4) & 3)) * 64 + bg * 16) * 512 +
                         (tid < 8 ? tid * 64 : 0);
        while (true) {
          u32 bpw = 0;
          UC_LOAD4(h0, ph);
          UC_LOAD4(h1, ph + 4);
          UC_LOAD4(h2, ph + 8);
          UC_LOAD4(h3, ph + 12);
          UC_LOAD1(bpw, pbp);
          asm volatile("s_waitcnt vmcnt(0)"
                       : "+v"(h0), "+v"(h1), "+v"(h2), "+v"(h3), "+v"(bpw)::"memory");
          bool ok = tag4(h0, exp_h) && tag4(h1, exp_h) && tag4(h2, exp_h) &&
                    tag4(h3, exp_h) && (!need_bp || ((bpw & 7u) == exp_bp));
          if (__all(ok)) break;
        }
      }
    } else {
      // layer1: poll in0 = out0[s] (always) + own-layer H (s>1)
      i32x4 i0 = {0, 0, 0, 0}, i1 = {0, 0, 0, 0}, i2 = {0, 0, 0, 0}, i3 = {0, 0, 0, 0};
      const u32 exp_i = (u32)(s & 7);
      const u32* pi =
          hsl + (((size_t)(s & 3)) * 64 + bg * 16 + r_st) * 512 + ch * 16;
      const bool need_h = (s > 1);
      while (true) {
        UC_LOAD4(i0, pi);
        UC_LOAD4(i1, pi + 4);
        UC_LOAD4(i2, pi + 8);
        UC_LOAD4(i3, pi + 12);
        UC_LOAD4(h0, ph);
        UC_LOAD4(h1, ph + 4);
        UC_LOAD4(h2, ph + 8);
        UC_LOAD4(h3, ph + 12);
        asm volatile("s_waitcnt vmcnt(0)"
                     : "+v"(i0), "+v"(i1), "+v"(i2), "+v"(i3), "+v"(h0), "+v"(h1),
                       "+v"(h2), "+v"(h3)::"memory");
        bool ok = tag4(i0, exp_i) && tag4(i1, exp_i) && tag4(i2, exp_i) &&
                  tag4(i3, exp_i) &&
                  (!need_h || (tag4(h0, exp_h) && tag4(h1, exp_h) &&
                               tag4(h2, exp_h) && tag4(h3, exp_h)));
        if (__all(ok)) break;
      }
      // stage in0 (hi halves only) into swizzled LDS
      i32x4 A0 = {(int)hipack(i0[0], i0[1]), (int)hipack(i0[2], i0[3]),
                  (int)hipack(i1[0], i1[1]), (int)hipack(i1[2], i1[3])};
      i32x4 A1 = {(int)hipack(i2[0], i2[1]), (int)hipack(i2[2], i2[3]),
                  (int)hipack(i3[0], i3[1]), (int)hipack(i3[2], i3[3])};
      *(i32x4*)(s_in0 + r_st * 512 + (((2 * ch) ^ (r_st & 7)) << 3)) = A0;
      *(i32x4*)(s_in0 + r_st * 512 + (((2 * ch + 1) ^ (r_st & 7)) << 3)) = A1;
    }

    // ---- stage in0 for layer0 (from prefetched emb f32) ----
    if (layer == 0) {
      i32x4 v0, v1;
      v0[0] = pack2(f2bf(pf0.x), f2bf(pf0.y));
      v0[1] = pack2(f2bf(pf0.z), f2bf(pf0.w));
      v0[2] = pack2(f2bf(pf1.x), f2bf(pf1.y));
      v0[3] = pack2(f2bf(pf1.z), f2bf(pf1.w));
      v1[0] = pack2(f2bf(pf2.x), f2bf(pf2.y));
      v1[1] = pack2(f2bf(pf2.z), f2bf(pf2.w));
      v1[2] = pack2(f2bf(pf3.x), f2bf(pf3.y));
      v1[3] = pack2(f2bf(pf3.z), f2bf(pf3.w));
      *(i32x4*)(s_in0 + r_st * 512 + (((2 * ch) ^ (r_st & 7)) << 3)) = v0;
      *(i32x4*)(s_in0 + r_st * 512 + (((2 * ch + 1) ^ (r_st & 7)) << 3)) = v1;
    }
    // ---- stage H hi/lo (deinterleave tagged words) ----
    if (s > 1) {
      i32x4 A0 = {(int)hipack(h0[0], h0[1]), (int)hipack(h0[2], h0[3]),
                  (int)hipack(h1[0], h1[1]), (int)hipack(h1[2], h1[3])};
      i32x4 A1 = {(int)hipack(h2[0], h2[1]), (int)hipack(h2[2], h2[3]),
                  (int)hipack(h3[0], h3[1]), (int)hipack(h3[2], h3[3])};
      i32x4 B0 = {(int)lopack(h0[0], h0[1]), (int)lopack(h0[2], h0[3]),
                  (int)lopack(h1[0], h1[1]), (int)lopack(h1[2], h1[3])};
      i32x4 B1 = {(int)lopack(h2[0], h2[1]), (int)lopack(h2[2], h2[3]),
                  (int)lopack(h3[0], h3[1]), (int)lopack(h3[2], h3[3])};
      *(i32x4*)(s_Hhi + r_st * 512 + (((2 * ch) ^ (r_st & 7)) << 3)) = A0;
      *(i32x4*)(s_Hhi + r_st * 512 + (((2 * ch + 1) ^ (r_st & 7)) << 3)) = A1;
      *(i32x4*)(s_Hlo + r_st * 512 + (((2 * ch) ^ (r_st & 7)) << 3)) = B0;
      *(i32x4*)(s_Hlo + r_st * 512 + (((2 * ch + 1) ^ (r_st & 7)) << 3)) = B1;
    }
    __syncthreads();  // B2

    // ---- prefetch next emb row (layer0, off critical path) ----
    if (layer == 0 && s < SS) {
      int rid = x[(bg * 16 + r_st) * SS + s];
      const float4* ep = (const float4*)(emb + (size_t)rid * 512 + ch * 16);
      pf0 = ep[0]; pf1 = ep[1]; pf2 = ep[2]; pf3 = ep[3];
    }

    // ---- MFMA ----
    f32x4 acc0 = {0.f, 0.f, 0.f, 0.f};
    f32x4 acc1 = {0.f, 0.f, 0.f, 0.f};
    {
      const int r16 = lane & 15, kg = lane >> 4;
#pragma unroll
      for (int kt = 0; kt < 4; ++kt) {
        int k8 = kq * 16 + kt * 4 + kg;
        bf16x8 ain = __builtin_bit_cast(
            bf16x8, *(const i32x4*)(s_in0 + r16 * 512 + ((k8 ^ (r16 & 7)) << 3)));
        acc0 = __builtin_amdgcn_mfma_f32_16x16x32_bf16(ain, wih[0][kt], acc0, 0, 0, 0);
        acc1 = __builtin_amdgcn_mfma_f32_16x16x32_bf16(ain, wih[1][kt], acc1, 0, 0, 0);
      }
      if (s > 1) {
#pragma unroll
        for (int kt = 0; kt < 4; ++kt) {
          int k8 = kq * 16 + kt * 4 + kg;
          bf16x8 ahi = __builtin_bit_cast(
              bf16x8, *(const i32x4*)(s_Hhi + r16 * 512 + ((k8 ^ (r16 & 7)) << 3)));
          bf16x8 alo = __builtin_bit_cast(
              bf16x8, *(const i32x4*)(s_Hlo + r16 * 512 + ((k8 ^ (r16 & 7)) << 3)));
          acc0 = __builtin_amdgcn_mfma_f32_16x16x32_bf16(ahi, whhh[0][kt], acc0, 0, 0, 0);
          acc0 = __builtin_amdgcn_mfma_f32_16x16x32_bf16(ahi, whhl[0][kt], acc0, 0, 0, 0);
          acc0 = __builtin_amdgcn_mfma_f32_16x16x32_bf16(alo, whhh[0][kt], acc0, 0, 0, 0);
          acc1 = __builtin_amdgcn_mfma_f32_16x16x32_bf16(ahi, whhh[1][kt], acc1, 0, 0, 0);
          acc1 = __builtin_amdgcn_mfma_f32_16x16x32_bf16(ahi, whhl[1][kt], acc1, 0, 0, 0);
          acc1 = __builtin_amdgcn_mfma_f32_16x16x32_bf16(alo, whhh[1][kt], acc1, 0, 0, 0);
        }
      }
#pragma unroll
      for (int j = 0; j < 4; ++j) {
        int m = kg * 4 + j;
        int xr = (m >> 2) & 3;
        int n0i = nh * 32 + 0 * 16 + r16;
        int n1i = nh * 32 + 1 * 16 + r16;
        s_part[kq * SPART_Q + m * SPART_LD + (n0i ^ (xr << 4))] = acc0[j];
        s_part[kq * SPART_Q + m * SPART_LD + (n1i ^ (xr << 4))] = acc1[j];
      }
    }
    __syncthreads();  // B3

    // ---- finals: reduce, bias, fast-tanh, pack word (hi|lo|tag), publish ----
    {
      int m = tid >> 5, na = (tid & 31) * 2;
      int xr = (m >> 2) & 3;
      float v0 = biasv0, v1 = biasv1;
#pragma unroll
      for (int q2 = 0; q2 < 4; ++q2) {
        const float2* sp =
            (const float2*)(s_part + q2 * SPART_Q + m * SPART_LD + (na ^ (xr << 4)));
        float2 t = *sp;
        v0 += t.x;
        v1 += t.y;
      }
      v0 = fast_tanh(v0);
      v1 = fast_tanh(v1);
      unsigned short a0 = f2bf(v0), a1 = f2bf(v1);
      unsigned short b0 = f2bf(v0 - bf2f(a0)), b1 = f2bf(v1 - bf2f(a1));
      u32 tag = (u32)(s & 7);
      u32x2 wv;
      wv[0] = ((u32)a0 << 16) | ((u32)b0 & 0xFFF8u) | tag;
      wv[1] = ((u32)a1 << 16) | ((u32)b1 & 0xFFF8u) | tag;
      u32* dst = hsl + (((size_t)layer * 4 + (s & 3)) * 64 + bg * 16 + m) * 512 +
                 c * 64 + na;
      UC_STORE2(dst, wv);
    }
    // no drain, no flag: consumers detect via embedded tags
  }
}

__global__ void k_fc(const u32* __restrict__ h1w, const float* __restrict__ fcW,
                     const float* __restrict__ fcb, float* __restrict__ out) {
  int i = threadIdx.x;  // 512 = 64 batch x 8 classes
  int b = i >> 3, cc = i & 7;
  float acc = fcb[cc];
  const u32* ph = h1w + b * 512;
  const float* pw = fcW + cc * 512;
  for (int k = 0; k < 512; k += 4) {
    int4 w4 = *(const int4*)(ph + k);
    float4 wv = *(const float4*)(pw + k);
    acc += (bf2f((unsigned short)((u32)w4.x >> 16)) +
            bf2f((unsigned short)((u32)w4.x & 0xFFF8u))) * wv.x;
    acc += (bf2f((unsigned short)((u32)w4.y >> 16)) +
            bf2f((unsigned short)((u32)w4.y & 0xFFF8u))) * wv.y;
    acc += (bf2f((unsigned short)((u32)w4.z >> 16)) +
            bf2f((unsigned short)((u32)w4.z & 0xFFF8u))) * wv.z;
    acc += (bf2f((unsigned short)((u32)w4.w >> 16)) +
            bf2f((unsigned short)((u32)w4.w & 0xFFF8u))) * wv.w;
  }
  out[b * 8 + cc] = acc;
}

extern "C" void kernel_launch(void* const* d_in, const int* in_sizes, int n_in,
                              void* d_out, int out_size, void* d_ws, size_t ws_size,
                              hipStream_t stream) {
  const int* x = (const int*)d_in[0];
  const float* emb = (const float*)d_in[1];
  const float* Wih0 = (const float*)d_in[2];
  const float* Whh0 = (const float*)d_in[3];
  const float* bih0 = (const float*)d_in[4];
  const float* bhh0 = (const float*)d_in[5];
  const float* Wih1 = (const float*)d_in[6];
  const float* Whh1 = (const float*)d_in[7];
  const float* bih1 = (const float*)d_in[8];
  const float* bhh1 = (const float*)d_in[9];
  const float* fcW = (const float*)d_in[10];
  const float* fcb = (const float*)d_in[11];

  u32* hsl = (u32*)d_ws;  // 2 layers x 4 slots x 64 x 512 u32 = 1 MB

  hipMemsetAsync(hsl, 0, (size_t)2 * 4 * 64 * 512 * 4, stream);
  hipLaunchKernelGGL(k_rnn, dim3(64), dim3(512), 0, stream, x, emb, Wih0, Whh0,
                     bih0, bhh0, Wih1, Whh1, bih1, bhh1, hsl);
  // final h1 = step 512 -> layer1 slot (512&3)==0
  hipLaunchKernelGGL(k_fc, dim3(1), dim3(512), 0, stream,
                     hsl + (size_t)4 * 64 * 512, fcW, fcb, (float*)d_out);
}

// Round 5
// 2073.695 us; speedup vs baseline: 11.3448x; 1.0688x over previous
//
#include <hip/hip_runtime.h>
#include <stdint.h>

// RNNTextClassifier: B=64, S=512, E=H=512, NCLS=8
// Round 8: R6 protocol (proven 2216us) + safe step reorder.
// R7's NaN traced to pre-issued inline-asm poll loads living across
// __syncthreads + MFMA regions (regalloc copies read stale phys regs —
// m214 r263/r282 hazard class). R8 keeps every poll SELF-CONTAINED
// (load+waitcnt+check adjacent, proven R3/R6 shape) and only reorders
// the step so h-independent work precedes the H wait:
//   [stage in0 (+L1: in0 poll)] -> B1 -> [in0 MFMAs] ->
//   [H poll (+L0: bp) + stage H] -> B2 -> [H MFMAs + s_part] -> B3 ->
//   [finals/publish]
// Also: s_part stride reverted 68->64 (R6 pad RAISED conflicts 2.5->2.9e7).
// Ring: hsl[layer][slot=s&3][row 0..63][col 0..511] u32; tag = s&7.
// ws: hsl 1MB at offset 0 (memset to 0 each launch).

#define BB 64
#define SS 512
#define HH 512

typedef short bf16x8 __attribute__((ext_vector_type(8)));
typedef float f32x4 __attribute__((ext_vector_type(4)));
typedef int i32x4 __attribute__((ext_vector_type(4)));
typedef unsigned int u32;
typedef u32 u32x2 __attribute__((ext_vector_type(2)));

__device__ __forceinline__ unsigned short f2bf(float f) {
  uint32_t u = __builtin_bit_cast(uint32_t, f);
  u += 0x7FFFu + ((u >> 16) & 1u);
  return (unsigned short)(u >> 16);
}
__device__ __forceinline__ float bf2f(unsigned short h) {
  uint32_t u = ((uint32_t)h) << 16;
  return __builtin_bit_cast(float, u);
}
__device__ __forceinline__ int pack2(unsigned short a, unsigned short b) {
  return (int)(unsigned int)a | ((int)(unsigned int)b << 16);
}
// pack hi halves of two words into one u32 (elem a -> low half, b -> high)
__device__ __forceinline__ u32 hipack(u32 a, u32 b) {
  return (a >> 16) | (b & 0xFFFF0000u);
}
// pack lo halves (tag bits stripped)
__device__ __forceinline__ u32 lopack(u32 a, u32 b) {
  return (a & 0xFFF8u) | ((b & 0xFFF8u) << 16);
}
__device__ __forceinline__ bool tag4(i32x4 v, u32 t) {
  u32 m = (((u32)v[0] ^ t) | ((u32)v[1] ^ t) | ((u32)v[2] ^ t) | ((u32)v[3] ^ t)) & 7u;
  return m == 0u;
}
// fast tanh: t = sign(v) * (1 - e)/(1 + e), e = exp(-2|v|). No overflow,
// monotone, |err| ~1e-7. Uses HW v_exp_f32 via __expf.
__device__ __forceinline__ float fast_tanh(float v) {
  float a = __builtin_fabsf(v);
  float e = __expf(-2.0f * a);
  float t = (1.0f - e) / (1.0f + e);
  return __builtin_copysignf(t, v);
}

// device-coherent (UC) loads/stores: bypass non-common caches
#define UC_LOAD4(dst, ptr) \
  asm volatile("global_load_dwordx4 %0, %1, off sc0 sc1" : "=v"(dst) : "v"(ptr))
#define UC_LOAD1(dst, ptr) \
  asm volatile("global_load_dword %0, %1, off sc0 sc1" : "=v"(dst) : "v"(ptr))
#define UC_STORE2(ptr, v) \
  asm volatile("global_store_dwordx2 %0, %1, off sc0 sc1" ::"v"(ptr), "v"(v) : "memory")

__global__ __launch_bounds__(512, 2) void k_rnn(
    const int* __restrict__ x, const float* __restrict__ emb,
    const float* __restrict__ Wih0, const float* __restrict__ Whh0,
    const float* __restrict__ bih0, const float* __restrict__ bhh0,
    const float* __restrict__ Wih1, const float* __restrict__ Whh1,
    const float* __restrict__ bih1, const float* __restrict__ bhh1,
    u32* __restrict__ hsl) {
  const int tid = threadIdx.x;
  const int bid = blockIdx.x;
  const int layer = bid >> 5;  // 0 or 1
  const int lb = bid & 31;
  const int bg = lb >> 3;  // batch group (16 rows)
  const int c = lb & 7;    // hidden slice (64 dims)
  const int wid = tid >> 6;
  const int lane = tid & 63;
  const int kq = wid >> 1;  // K-quarter
  const int nh = wid & 1;   // N-half (32 cols)

  __shared__ __align__(16) unsigned short s_in0[16 * 512];
  __shared__ __align__(16) unsigned short s_Hhi[16 * 512];
  __shared__ __align__(16) unsigned short s_Hlo[16 * 512];
  __shared__ __align__(16) float s_part[4 * 16 * 64];

  const float* Wih = layer ? Wih1 : Wih0;
  const float* Whh = layer ? Whh1 : Whh0;
  const float* bi = layer ? bih1 : bih0;
  const float* bh = layer ? bhh1 : bhh0;

  // ---- one-time: W fragments into VGPRs ----
  bf16x8 wih[2][4], whhh[2][4], whhl[2][4];
  {
    const int r16 = lane & 15, kg = lane >> 4;
#pragma unroll
    for (int nt = 0; nt < 2; ++nt) {
#pragma unroll
      for (int kt = 0; kt < 4; ++kt) {
        int row = c * 64 + nh * 32 + nt * 16 + r16;
        int k0 = kq * 128 + kt * 32 + kg * 8;
        const float* p = Wih + row * 512 + k0;
        bf16x8 v;
#pragma unroll
        for (int j = 0; j < 8; ++j) v[j] = (short)f2bf(p[j]);
        wih[nt][kt] = v;
        const float* q = Whh + row * 512 + k0;
        bf16x8 vh, vl;
#pragma unroll
        for (int j = 0; j < 8; ++j) {
          float f = q[j];
          unsigned short h = f2bf(f);
          vh[j] = (short)h;
          vl[j] = (short)f2bf(f - bf2f(h));
        }
        whhh[nt][kt] = vh;
        whhl[nt][kt] = vl;
      }
    }
  }
  float biasv0, biasv1;
  {
    int na = (tid & 31) * 2;
    biasv0 = bi[c * 64 + na] + bh[c * 64 + na];
    biasv1 = bi[c * 64 + na + 1] + bh[c * 64 + na + 1];
  }

  const int r_st = tid >> 5;  // staging row 0..15
  const int ch = tid & 31;    // 16-element chunk of 512

  // prefetch in0 for step 1 (layer0: emb gather t=0)
  float4 pf0, pf1, pf2, pf3;
  if (layer == 0) {
    int rid = x[(bg * 16 + r_st) * SS + 0];
    const float4* ep = (const float4*)(emb + (size_t)rid * 512 + ch * 16);
    pf0 = ep[0]; pf1 = ep[1]; pf2 = ep[2]; pf3 = ep[3];
  }

  for (int s = 1; s <= SS; ++s) {
    const u32 exp_h = (u32)((s - 1) & 7);
    const u32* ph = hsl +
        (((size_t)layer * 4 + ((s - 1) & 3)) * 64 + bg * 16 + r_st) * 512 + ch * 16;

    // ============ pre-poll phase: h-independent work ============
    if (layer == 0) {
      // stage in0 from prefetched emb f32 (swizzled LDS)
      i32x4 v0, v1;
      v0[0] = pack2(f2bf(pf0.x), f2bf(pf0.y));
      v0[1] = pack2(f2bf(pf0.z), f2bf(pf0.w));
      v0[2] = pack2(f2bf(pf1.x), f2bf(pf1.y));
      v0[3] = pack2(f2bf(pf1.z), f2bf(pf1.w));
      v1[0] = pack2(f2bf(pf2.x), f2bf(pf2.y));
      v1[1] = pack2(f2bf(pf2.z), f2bf(pf2.w));
      v1[2] = pack2(f2bf(pf3.x), f2bf(pf3.y));
      v1[3] = pack2(f2bf(pf3.z), f2bf(pf3.w));
      *(i32x4*)(s_in0 + r_st * 512 + (((2 * ch) ^ (r_st & 7)) << 3)) = v0;
      *(i32x4*)(s_in0 + r_st * 512 + (((2 * ch + 1) ^ (r_st & 7)) << 3)) = v1;
      // issue emb prefetch for s+1 (plain loads; hide under B1+MFMA+poll)
      if (s < SS) {
        int rid = x[(bg * 16 + r_st) * SS + s];
        const float4* ep = (const float4*)(emb + (size_t)rid * 512 + ch * 16);
        pf0 = ep[0]; pf1 = ep[1]; pf2 = ep[2]; pf3 = ep[3];
      }
    } else {
      // layer1: poll in0 = out0[s] (self-contained spin, proven shape)
      i32x4 i0 = {0, 0, 0, 0}, i1 = {0, 0, 0, 0}, i2 = {0, 0, 0, 0}, i3 = {0, 0, 0, 0};
      const u32 exp_i = (u32)(s & 7);
      const u32* pi =
          hsl + (((size_t)(s & 3)) * 64 + bg * 16 + r_st) * 512 + ch * 16;
      while (true) {
        UC_LOAD4(i0, pi);
        UC_LOAD4(i1, pi + 4);
        UC_LOAD4(i2, pi + 8);
        UC_LOAD4(i3, pi + 12);
        asm volatile("s_waitcnt vmcnt(0)"
                     : "+v"(i0), "+v"(i1), "+v"(i2), "+v"(i3)::"memory");
        bool ok = tag4(i0, exp_i) && tag4(i1, exp_i) && tag4(i2, exp_i) &&
                  tag4(i3, exp_i);
        if (__all(ok)) break;
      }
      // stage in0 (hi halves only) into swizzled LDS
      i32x4 A0 = {(int)hipack(i0[0], i0[1]), (int)hipack(i0[2], i0[3]),
                  (int)hipack(i1[0], i1[1]), (int)hipack(i1[2], i1[3])};
      i32x4 A1 = {(int)hipack(i2[0], i2[1]), (int)hipack(i2[2], i2[3]),
                  (int)hipack(i3[0], i3[1]), (int)hipack(i3[2], i3[3])};
      *(i32x4*)(s_in0 + r_st * 512 + (((2 * ch) ^ (r_st & 7)) << 3)) = A0;
      *(i32x4*)(s_in0 + r_st * 512 + (((2 * ch + 1) ^ (r_st & 7)) << 3)) = A1;
    }
    __syncthreads();  // B1: s_in0 staged

    // ---- in0 MFMAs (h-independent: hide under producer publish) ----
    f32x4 acc0 = {0.f, 0.f, 0.f, 0.f};
    f32x4 acc1 = {0.f, 0.f, 0.f, 0.f};
    {
      const int r16 = lane & 15, kg = lane >> 4;
#pragma unroll
      for (int kt = 0; kt < 4; ++kt) {
        int k8 = kq * 16 + kt * 4 + kg;
        bf16x8 ain = __builtin_bit_cast(
            bf16x8, *(const i32x4*)(s_in0 + r16 * 512 + ((k8 ^ (r16 & 7)) << 3)));
        acc0 = __builtin_amdgcn_mfma_f32_16x16x32_bf16(ain, wih[0][kt], acc0, 0, 0, 0);
        acc1 = __builtin_amdgcn_mfma_f32_16x16x32_bf16(ain, wih[1][kt], acc1, 0, 0, 0);
      }
    }

    // ============ H poll (self-contained) + stage ============
    if (s > 1) {
      i32x4 h0 = {0, 0, 0, 0}, h1 = {0, 0, 0, 0}, h2 = {0, 0, 0, 0}, h3 = {0, 0, 0, 0};
      if (layer == 0) {
        const bool need_bp = (s > 4) && (tid < 8);
        const u32 exp_bp = (u32)((s - 4) & 7);
        const u32* pbp = hsl + ((size_t)(4 + ((s - 4) & 3)) * 64 + bg * 16) * 512 +
                         (tid < 8 ? tid * 64 : 0);
        while (true) {
          u32 bpw = 0;
          UC_LOAD4(h0, ph);
          UC_LOAD4(h1, ph + 4);
          UC_LOAD4(h2, ph + 8);
          UC_LOAD4(h3, ph + 12);
          UC_LOAD1(bpw, pbp);
          asm volatile("s_waitcnt vmcnt(0)"
                       : "+v"(h0), "+v"(h1), "+v"(h2), "+v"(h3), "+v"(bpw)::"memory");
          bool ok = tag4(h0, exp_h) && tag4(h1, exp_h) && tag4(h2, exp_h) &&
                    tag4(h3, exp_h) && (!need_bp || ((bpw & 7u) == exp_bp));
          if (__all(ok)) break;
        }
      } else {
        while (true) {
          UC_LOAD4(h0, ph);
          UC_LOAD4(h1, ph + 4);
          UC_LOAD4(h2, ph + 8);
          UC_LOAD4(h3, ph + 12);
          asm volatile("s_waitcnt vmcnt(0)"
                       : "+v"(h0), "+v"(h1), "+v"(h2), "+v"(h3)::"memory");
          bool ok = tag4(h0, exp_h) && tag4(h1, exp_h) && tag4(h2, exp_h) &&
                    tag4(h3, exp_h);
          if (__all(ok)) break;
        }
      }
      // stage H hi/lo (deinterleave tagged words)
      i32x4 A0 = {(int)hipack(h0[0], h0[1]), (int)hipack(h0[2], h0[3]),
                  (int)hipack(h1[0], h1[1]), (int)hipack(h1[2], h1[3])};
      i32x4 A1 = {(int)hipack(h2[0], h2[1]), (int)hipack(h2[2], h2[3]),
                  (int)hipack(h3[0], h3[1]), (int)hipack(h3[2], h3[3])};
      i32x4 B0 = {(int)lopack(h0[0], h0[1]), (int)lopack(h0[2], h0[3]),
                  (int)lopack(h1[0], h1[1]), (int)lopack(h1[2], h1[3])};
      i32x4 B1v = {(int)lopack(h2[0], h2[1]), (int)lopack(h2[2], h2[3]),
                   (int)lopack(h3[0], h3[1]), (int)lopack(h3[2], h3[3])};
      *(i32x4*)(s_Hhi + r_st * 512 + (((2 * ch) ^ (r_st & 7)) << 3)) = A0;
      *(i32x4*)(s_Hhi + r_st * 512 + (((2 * ch + 1) ^ (r_st & 7)) << 3)) = A1;
      *(i32x4*)(s_Hlo + r_st * 512 + (((2 * ch) ^ (r_st & 7)) << 3)) = B0;
      *(i32x4*)(s_Hlo + r_st * 512 + (((2 * ch + 1) ^ (r_st & 7)) << 3)) = B1v;
    }
    __syncthreads();  // B2: s_H staged

    // ---- H MFMAs + partial-sum write ----
    {
      const int r16 = lane & 15, kg = lane >> 4;
      if (s > 1) {
#pragma unroll
        for (int kt = 0; kt < 4; ++kt) {
          int k8 = kq * 16 + kt * 4 + kg;
          bf16x8 ahi = __builtin_bit_cast(
              bf16x8, *(const i32x4*)(s_Hhi + r16 * 512 + ((k8 ^ (r16 & 7)) << 3)));
          bf16x8 alo = __builtin_bit_cast(
              bf16x8, *(const i32x4*)(s_Hlo + r16 * 512 + ((k8 ^ (r16 & 7)) << 3)));
          acc0 = __builtin_amdgcn_mfma_f32_16x16x32_bf16(ahi, whhh[0][kt], acc0, 0, 0, 0);
          acc0 = __builtin_amdgcn_mfma_f32_16x16x32_bf16(ahi, whhl[0][kt], acc0, 0, 0, 0);
          acc0 = __builtin_amdgcn_mfma_f32_16x16x32_bf16(alo, whhh[0][kt], acc0, 0, 0, 0);
          acc1 = __builtin_amdgcn_mfma_f32_16x16x32_bf16(ahi, whhh[1][kt], acc1, 0, 0, 0);
          acc1 = __builtin_amdgcn_mfma_f32_16x16x32_bf16(ahi, whhl[1][kt], acc1, 0, 0, 0);
          acc1 = __builtin_amdgcn_mfma_f32_16x16x32_bf16(alo, whhh[1][kt], acc1, 0, 0, 0);
        }
      }
#pragma unroll
      for (int j = 0; j < 4; ++j) {
        int m = kg * 4 + j;
        int xr = (m >> 2) & 3;
        int n0i = nh * 32 + 0 * 16 + r16;
        int n1i = nh * 32 + 1 * 16 + r16;
        s_part[kq * 1024 + m * 64 + (n0i ^ (xr << 4))] = acc0[j];
        s_part[kq * 1024 + m * 64 + (n1i ^ (xr << 4))] = acc1[j];
      }
    }
    __syncthreads();  // B3

    // ---- finals: reduce, bias, fast-tanh, pack word (hi|lo|tag), publish ----
    {
      int m = tid >> 5, na = (tid & 31) * 2;
      int xr = (m >> 2) & 3;
      float v0 = biasv0, v1 = biasv1;
#pragma unroll
      for (int q2 = 0; q2 < 4; ++q2) {
        const float2* sp =
            (const float2*)(s_part + q2 * 1024 + m * 64 + (na ^ (xr << 4)));
        float2 t = *sp;
        v0 += t.x;
        v1 += t.y;
      }
      v0 = fast_tanh(v0);
      v1 = fast_tanh(v1);
      unsigned short a0 = f2bf(v0), a1 = f2bf(v1);
      unsigned short b0 = f2bf(v0 - bf2f(a0)), b1 = f2bf(v1 - bf2f(a1));
      u32 tag = (u32)(s & 7);
      u32x2 wv;
      wv[0] = ((u32)a0 << 16) | ((u32)b0 & 0xFFF8u) | tag;
      wv[1] = ((u32)a1 << 16) | ((u32)b1 & 0xFFF8u) | tag;
      u32* dst = hsl + (((size_t)layer * 4 + (s & 3)) * 64 + bg * 16 + m) * 512 +
                 c * 64 + na;
      UC_STORE2(dst, wv);
    }
    // no drain, no flag: consumers detect via embedded tags
  }
}

__global__ void k_fc(const u32* __restrict__ h1w, const float* __restrict__ fcW,
                     const float* __restrict__ fcb, float* __restrict__ out) {
  int i = threadIdx.x;  // 512 = 64 batch x 8 classes
  int b = i >> 3, cc = i & 7;
  float acc = fcb[cc];
  const u32* ph = h1w + b * 512;
  const float* pw = fcW + cc * 512;
  for (int k = 0; k < 512; k += 4) {
    int4 w4 = *(const int4*)(ph + k);
    float4 wv = *(const float4*)(pw + k);
    acc += (bf2f((unsigned short)((u32)w4.x >> 16)) +
            bf2f((unsigned short)((u32)w4.x & 0xFFF8u))) * wv.x;
    acc += (bf2f((unsigned short)((u32)w4.y >> 16)) +
            bf2f((unsigned short)((u32)w4.y & 0xFFF8u))) * wv.y;
    acc += (bf2f((unsigned short)((u32)w4.z >> 16)) +
            bf2f((unsigned short)((u32)w4.z & 0xFFF8u))) * wv.z;
    acc += (bf2f((unsigned short)((u32)w4.w >> 16)) +
            bf2f((unsigned short)((u32)w4.w & 0xFFF8u))) * wv.w;
  }
  out[b * 8 + cc] = acc;
}

extern "C" void kernel_launch(void* const* d_in, const int* in_sizes, int n_in,
                              void* d_out, int out_size, void* d_ws, size_t ws_size,
                              hipStream_t stream) {
  const int* x = (const int*)d_in[0];
  const float* emb = (const float*)d_in[1];
  const float* Wih0 = (const float*)d_in[2];
  const float* Whh0 = (const float*)d_in[3];
  const float* bih0 = (const float*)d_in[4];
  const float* bhh0 = (const float*)d_in[5];
  const float* Wih1 = (const float*)d_in[6];
  const float* Whh1 = (const float*)d_in[7];
  const float* bih1 = (const float*)d_in[8];
  const float* bhh1 = (const float*)d_in[9];
  const float* fcW = (const float*)d_in[10];
  const float* fcb = (const float*)d_in[11];

  u32* hsl = (u32*)d_ws;  // 2 layers x 4 slots x 64 x 512 u32 = 1 MB

  hipMemsetAsync(hsl, 0, (size_t)2 * 4 * 64 * 512 * 4, stream);
  hipLaunchKernelGGL(k_rnn, dim3(64), dim3(512), 0, stream, x, emb, Wih0, Whh0,
                     bih0, bhh0, Wih1, Whh1, bih1, bhh1, hsl);
  // final h1 = step 512 -> layer1 slot (512&3)==0
  hipLaunchKernelGGL(k_fc, dim3(1), dim3(512), 0, stream,
                     hsl + (size_t)4 * 64 * 512, fcW, fcb, (float*)d_out);
}